// Round 17
// baseline (3993.310 us; speedup 1.0000x reference)
//
#include <hip/hip_runtime.h>
#include <stdint.h>

typedef __attribute__((ext_vector_type(4))) float f32x4;
typedef __attribute__((ext_vector_type(4))) int i32x4;
typedef __attribute__((ext_vector_type(4))) unsigned short u16x4;
typedef __attribute__((ext_vector_type(8))) __bf16 bf16x8;

#define NB 64
#define TD 256
#define TE 256
#define HH 512
#define DD 256
#define FH 2048
#define KT 768
#define LDK 776  // LDS row stride (bf16)

// workspace layout (bytes)
#define WS_ENC   0u          // ushort [NB][TE][HH]   enc bf16
#define WS_ENCT  16777216u   // ushort [NB][HH][TE]   enc transposed bf16
#define WS_DEC   33554432u   // ushort [NB][TD][HH]   dec_outputs bf16
#define WS_HPING 50331648u   // ushort [2][NB][HH]    h ping-pong bf16
#define WS_CNT   50462720u   // uint   [2][TD]        arrival counters
#define WS_WT    50528256u   // ushort [FH][KT]       W|U transposed bf16 (3MB)
#define WS_XSEQ  53673984u   // ushort [TD][NB][DD]   precomputed x bf16 (8MB)

#define OUT_HT 8388608u      // B*TD*H
#define OUT_CT 8421376u

__device__ inline unsigned short f2b(float f) {
  union { float f; unsigned u; } x; x.f = f;
  unsigned r = x.u + 0x7FFFu + ((x.u >> 16) & 1u);   // RNE
  return (unsigned short)(r >> 16);
}
__device__ inline float sigm(float x)   { return 1.0f / (1.0f + __expf(-x)); }
__device__ inline float tanhf_(float x) { return 1.0f - 2.0f / (__expf(2.0f * x) + 1.0f); }

__device__ inline f32x4 mfma_bf16(i32x4 a, i32x4 b, f32x4 c) {
  return __builtin_amdgcn_mfma_f32_16x16x32_bf16(
      __builtin_bit_cast(bf16x8, a), __builtin_bit_cast(bf16x8, b), c, 0, 0, 0);
}

// ---- L3-coherent primitives (bypass L1/L2: sc0 sc1) ----
__device__ inline unsigned poll_word(const unsigned* p) {
  unsigned v;
  asm volatile("global_load_dword %0, %1, off sc0 sc1\n\ts_waitcnt vmcnt(0)"
               : "=v"(v) : "v"(p) : "memory");
  return v;
}
__device__ inline i32x4 load4_bypass(const void* p) {  // NO waitcnt inside
  i32x4 v;
  asm volatile("global_load_dwordx4 %0, %1, off sc0 sc1" : "=v"(v) : "v"(p) : "memory");
  return v;
}
__device__ inline void store4_wt(void* p, i32x4 v) {  // 16B write-through
  asm volatile("global_store_dwordx4 %0, %1, off sc0 sc1" :: "v"(p), "v"(v) : "memory");
}
__device__ inline void store_u16_wt(unsigned short* p, unsigned v) {  // 2B write-through
  asm volatile("global_store_short %0, %1, off sc0 sc1" :: "v"(p), "v"(v) : "memory");
}
__device__ inline void vm_drain() {
  asm volatile("s_waitcnt vmcnt(0)" ::: "memory");
}
__device__ inline void lds_fence() {
  asm volatile("s_waitcnt lgkmcnt(0)" ::: "memory");
}

// ---------------- prepass: enc -> bf16 + transposed bf16 ----------------
__global__ __launch_bounds__(256) void enc_prep(const float* __restrict__ enc,
                                                unsigned short* __restrict__ enc_bf,
                                                unsigned short* __restrict__ encT_bf) {
  __shared__ float tile[64][65];
  const int bid = blockIdx.x;
  const int b  = bid >> 5;
  const int kt = (bid >> 3) & 3;
  const int ht = bid & 7;
  const int tr = threadIdx.x >> 6;
  const int tc = threadIdx.x & 63;
#pragma unroll
  for (int i = 0; i < 16; ++i) {
    const int ke = i * 4 + tr;
    const float v = enc[((size_t)b * TE + kt * 64 + ke) * HH + ht * 64 + tc];
    enc_bf[((size_t)b * TE + kt * 64 + ke) * HH + ht * 64 + tc] = f2b(v);
    tile[ke][tc] = v;
  }
  __syncthreads();
  const int hr4 = threadIdx.x >> 4;
  const int k4  = (threadIdx.x & 15) * 4;
#pragma unroll
  for (int jr = 0; jr < 4; ++jr) {
    const int hr = jr * 16 + hr4;
    u16x4 p = { f2b(tile[k4 + 0][hr]), f2b(tile[k4 + 1][hr]),
                f2b(tile[k4 + 2][hr]), f2b(tile[k4 + 3][hr]) };
    *(u16x4*)&encT_bf[((size_t)b * HH + ht * 64 + hr) * TE + kt * 64 + k4] = p;
  }
}

// ---------------- prepass: W|U -> bf16 transposed wT[col][k] ----------------
__global__ __launch_bounds__(256) void w_prep(const float* __restrict__ W,
                                              const float* __restrict__ U,
                                              unsigned short* __restrict__ wT) {
  __shared__ float tile[64][65];
  const int kt = blockIdx.x >> 5;
  const int ct = blockIdx.x & 31;
  const int tr = threadIdx.x >> 6;
  const int tc = threadIdx.x & 63;
#pragma unroll
  for (int i = 0; i < 16; ++i) {
    const int kr = i * 4 + tr;
    const int k  = kt * 64 + kr;
    const float v = (k < DD) ? W[(size_t)k * FH + ct * 64 + tc]
                             : U[(size_t)(k - DD) * FH + ct * 64 + tc];
    tile[kr][tc] = v;
  }
  __syncthreads();
  const int cr4 = threadIdx.x >> 4;
  const int k4  = (threadIdx.x & 15) * 4;
#pragma unroll
  for (int jr = 0; jr < 4; ++jr) {
    const int cr = jr * 16 + cr4;
    u16x4 p = { f2b(tile[k4 + 0][cr]), f2b(tile[k4 + 1][cr]),
                f2b(tile[k4 + 2][cr]), f2b(tile[k4 + 3][cr]) };
    *(u16x4*)&wT[((size_t)ct * 64 + cr) * KT + kt * 64 + k4] = p;
  }
}

// ---------------- prepass: gather x = E[ids] for ALL steps -> xseq[t][b][d] bf16 ----
__global__ __launch_bounds__(64) void x_prep(const float* __restrict__ E,
                                             const int* __restrict__ ids,
                                             unsigned short* __restrict__ xseq) {
  const int bid = blockIdx.x;       // 16384 = 64 b * 256 t
  const int b = bid >> 8;
  const int t = bid & 255;
  const int lane = threadIdx.x;
  const int id = ids[b * TD + t];
  f32x4 v = *(const f32x4*)(E + (size_t)id * DD + lane * 4);
  u16x4 p = { f2b(v[0]), f2b(v[1]), f2b(v[2]), f2b(v[3]) };
  *(u16x4*)&xseq[((size_t)t * NB + b) * DD + lane * 4] = p;
}

// ---------------- prepass: h0 -> bf16, zero counters ----------------
__global__ __launch_bounds__(256) void h0_prep(const float* __restrict__ h0,
                                               unsigned short* __restrict__ h_ping,
                                               unsigned* __restrict__ cnt) {
  const int i = blockIdx.x * 256 + threadIdx.x;
  if (i < NB * HH) h_ping[i] = f2b(h0[i]);
  if (i < 2 * TD) cnt[i] = 0u;
}

// ---------------- persistent masked LSTM, dual-chain interleaved ----------------
// 32 blocks, each owning unit-slice s (16 units) for BOTH batch-groups.
// The two groups are independent chains; alternating g0-step / g1-step puts
// the other chain's compute inside each chain's publish->poll window, hiding
// the L3 visibility latency. Weights are group-independent -> one LDS copy.
__global__ __launch_bounds__(64, 1) void lstm_kernel(
    const unsigned short* __restrict__ xseq, const int* __restrict__ ids,
    const float* __restrict__ h0f, const float* __restrict__ c0f,
    const unsigned short* __restrict__ wT, const float* __restrict__ bias,
    unsigned short* __restrict__ h_ping,
    unsigned short* __restrict__ dec_bf,
    float* __restrict__ out,
    unsigned* __restrict__ cnt)
{
  const int lane = threadIdx.x;
  const int s  = blockIdx.x;        // unit slice 0..31 (both groups)
  const int u0 = s << 4;
  const int lhi = lane >> 4;        // 0..3
  const int llo = lane & 15;

  __shared__ __align__(16) unsigned short wt[64 * LDK];  // 99.3KB (shared by both groups)
  __shared__ unsigned short ids_l[64][264];              // 33.8KB (u16, V<65536)
  __shared__ __align__(64) unsigned short hT[32][32];    // 2KB publish-transpose (reused)

  // stage weight slice
  {
    const int r = lane;
    const int c = (r >> 4) * 512 + u0 + (r & 15);
    const unsigned short* src = wT + (size_t)c * KT;
#pragma unroll 8
    for (int j = 0; j < 96; ++j)
      *(i32x4*)&wt[r * LDK + j * 8] = *(const i32x4*)(src + j * 8);
  }
  // stage ids for ALL 64 batches (u16)
  for (int idx = lane; idx < 64 * 256; idx += 64) {
    const int row = idx >> 8, tt = idx & 255;
    ids_l[row][tt] = (unsigned short)ids[row * TD + tt];
  }
  __syncthreads();

  float bb[4];
#pragma unroll
  for (int gg = 0; gg < 4; ++gg) bb[gg] = bias[gg * 512 + u0 + llo];

  float h_reg[2][2][4], c_reg[2][2][4];
#pragma unroll
  for (int gi = 0; gi < 2; ++gi)
#pragma unroll
    for (int mt = 0; mt < 2; ++mt)
#pragma unroll
      for (int r = 0; r < 4; ++r) {
        const int b = gi * 32 + mt * 16 + lhi * 4 + r;
        h_reg[gi][mt][r] = h0f[b * HH + u0 + llo];
        c_reg[gi][mt][r] = c0f[b * HH + u0 + llo];
      }

  unsigned short* hp0 = h_ping;
  unsigned short* hp1 = h_ping + NB * HH;

  for (int t = 0; t < TD; ++t) {
    const unsigned short* h_src = (t & 1) ? hp1 : hp0;
    unsigned short*       h_dst = (t & 1) ? hp0 : hp1;

#pragma unroll
    for (int gi = 0; gi < 2; ++gi) {
      int mid[2][4];
#pragma unroll
      for (int mt = 0; mt < 2; ++mt)
#pragma unroll
        for (int r = 0; r < 4; ++r)
          mid[mt][r] = ids_l[gi * 32 + mt * 16 + lhi * 4 + r][t];

      // x fragments: sequential bf16 loads from precomputed xseq
      const unsigned short* xp = xseq + ((size_t)t * NB + gi * 32) * DD;
      i32x4 xf[2][8];
#pragma unroll
      for (int mt = 0; mt < 2; ++mt) {
        const unsigned short* xr = xp + (mt * 16 + llo) * DD + lhi * 8;
#pragma unroll
        for (int kk = 0; kk < 8; ++kk)
          xf[mt][kk] = *(const i32x4*)(xr + kk * 32);
      }

      // x-part MFMAs (K = 0..255) — before waiting on this chain's peers
      f32x4 acc[2][4];
#pragma unroll
      for (int mt = 0; mt < 2; ++mt)
#pragma unroll
        for (int gg = 0; gg < 4; ++gg) acc[mt][gg] = (f32x4){0.f, 0.f, 0.f, 0.f};
#pragma unroll
      for (int kk = 0; kk < 8; ++kk) {
        const int ko = kk * 32 + lhi * 8;
#pragma unroll
        for (int gg = 0; gg < 4; ++gg) {
          i32x4 bfr = *(const i32x4*)&wt[(gg * 16 + llo) * LDK + ko];
          acc[0][gg] = mfma_bf16(xf[0][kk], bfr, acc[0][gg]);
          acc[1][gg] = mfma_bf16(xf[1][kk], bfr, acc[1][gg]);
        }
      }

      // wait for this chain's previous step (other chain's work filled the gap)
      if (t > 0) {
        const unsigned* c = cnt + (size_t)gi * TD + (t - 1);
        while (poll_word(c) < 32u) { /* hot spin: wave-merged single-dword poll */ }
      }

      // h-part MFMAs (K = 256..767)
      {
        const unsigned short* hb0 = h_src + (size_t)(gi * 32 + llo) * HH + lhi * 8;
        const unsigned short* hb1 = hb0 + 16 * HH;
        i32x4 ha0[16], ha1[16];
#pragma unroll
        for (int kk = 0; kk < 16; ++kk) {
          ha0[kk] = load4_bypass(hb0 + kk * 32);
          ha1[kk] = load4_bypass(hb1 + kk * 32);
        }
        vm_drain();
        __builtin_amdgcn_sched_barrier(0);  // rule #18: keep MFMAs after the waitcnt
#pragma unroll
        for (int kk = 0; kk < 16; ++kk) {
          const int ko = DD + kk * 32 + lhi * 8;
#pragma unroll
          for (int gg = 0; gg < 4; ++gg) {
            i32x4 bfr = *(const i32x4*)&wt[(gg * 16 + llo) * LDK + ko];
            acc[0][gg] = mfma_bf16(ha0[kk], bfr, acc[0][gg]);
            acc[1][gg] = mfma_bf16(ha1[kk], bfr, acc[1][gg]);
          }
        }
      }

      // epilogue: gates, state update; h -> LDS transpose tile; dec stores
      unsigned hb_out[2][4];
#pragma unroll
      for (int mt = 0; mt < 2; ++mt) {
#pragma unroll
        for (int r = 0; r < 4; ++r) {
          const float zi = acc[mt][0][r] + bb[0];
          const float zf = acc[mt][1][r] + bb[1];
          const float zg = acc[mt][2][r] + bb[2];
          const float zo = acc[mt][3][r] + bb[3];
          const float cn = sigm(zf) * c_reg[gi][mt][r] + sigm(zi) * tanhf_(zg);
          const float hn = sigm(zo) * tanhf_(cn);
          if (mid[mt][r] != 0) { c_reg[gi][mt][r] = cn; h_reg[gi][mt][r] = hn; }
          const unsigned hb = f2b(h_reg[gi][mt][r]);
          hb_out[mt][r] = hb;
          hT[mt * 16 + lhi * 4 + r][llo] = (unsigned short)hb;
          const int b = gi * 32 + mt * 16 + lhi * 4 + r;
          store_u16_wt(&dec_bf[((size_t)b * TD + t) * HH + u0 + llo], hb);
        }
      }

      if (t < TD - 1) {
        lds_fence();
        __builtin_amdgcn_sched_barrier(0);
        // coalesced publish: one 16B sector-aligned store per lane
        const int br = lane >> 1;
        const int half = lane & 1;
        i32x4 hv = *(const i32x4*)&hT[br][half * 8];
        store4_wt(h_dst + (size_t)(gi * 32 + br) * HH + u0 + half * 8, hv);
        vm_drain();  // h publish + dec stores acked -> nothing outstanding at next poll
        if (lane == 0)
          __hip_atomic_fetch_add(cnt + (size_t)gi * TD + t, 1u,
                                 __ATOMIC_RELEASE, __HIP_MEMORY_SCOPE_AGENT);
      }
    }
  }

#pragma unroll
  for (int gi = 0; gi < 2; ++gi)
#pragma unroll
    for (int mt = 0; mt < 2; ++mt)
#pragma unroll
      for (int r = 0; r < 4; ++r) {
        const int b = gi * 32 + mt * 16 + lhi * 4 + r;
        out[OUT_HT + (size_t)b * HH + u0 + llo] = h_reg[gi][mt][r];
        out[OUT_CT + (size_t)b * HH + u0 + llo] = c_reg[gi][mt][r];
      }
}

// ---------------- fused attention: scores -> softmax -> ctx ----------------
__global__ __launch_bounds__(64, 1) void attn_kernel(
    const unsigned short* __restrict__ dec_bf,
    const unsigned short* __restrict__ enc_bf,
    const unsigned short* __restrict__ encT_bf,
    const int* __restrict__ ids,
    float* __restrict__ out)
{
  const int lane = threadIdx.x;
  const int b  = blockIdx.x >> 4;
  const int q0 = (blockIdx.x & 15) << 4;
  const int lhi = lane >> 4, llo = lane & 15;

  __shared__ __align__(16) unsigned short plds[16 * 264];

  i32x4 qf[16];
  const unsigned short* qb = dec_bf + ((size_t)b * TD + q0 + llo) * HH + lhi * 8;
#pragma unroll
  for (int kk = 0; kk < 16; ++kk) qf[kk] = *(const i32x4*)(qb + kk * 32);

  f32x4 sc[16];
#pragma unroll
  for (int ke = 0; ke < 16; ++ke) sc[ke] = (f32x4){0.f, 0.f, 0.f, 0.f};
#pragma unroll
  for (int kk = 0; kk < 16; ++kk) {
    const unsigned short* eb = enc_bf + ((size_t)b * TE + llo) * HH + kk * 32 + lhi * 8;
#pragma unroll
    for (int ke = 0; ke < 16; ++ke)
      sc[ke] = mfma_bf16(qf[kk], *(const i32x4*)(eb + (size_t)ke * 16 * HH), sc[ke]);
  }

  float mx[4], rinv[4];
#pragma unroll
  for (int r = 0; r < 4; ++r) {
    float m = sc[0][r];
#pragma unroll
    for (int ke = 1; ke < 16; ++ke) m = fmaxf(m, sc[ke][r]);
#pragma unroll
    for (int off = 1; off <= 8; off <<= 1) m = fmaxf(m, __shfl_xor(m, off));
    mx[r] = m;
  }
  float sm[4] = {0.f, 0.f, 0.f, 0.f};
#pragma unroll
  for (int ke = 0; ke < 16; ++ke)
#pragma unroll
    for (int r = 0; r < 4; ++r) {
      const float p = __expf(sc[ke][r] - mx[r]);
      sc[ke][r] = p;
      sm[r] += p;
    }
#pragma unroll
  for (int r = 0; r < 4; ++r) {
    float ss = sm[r];
#pragma unroll
    for (int off = 1; off <= 8; off <<= 1) ss += __shfl_xor(ss, off);
    rinv[r] = 1.0f / ss;
  }

#pragma unroll
  for (int ke = 0; ke < 16; ++ke)
#pragma unroll
    for (int r = 0; r < 4; ++r)
      plds[(lhi * 4 + r) * 264 + ke * 16 + llo] = f2b(sc[ke][r]);
  __syncthreads();

  int mq[4];
#pragma unroll
  for (int r = 0; r < 4; ++r) mq[r] = ids[b * TD + q0 + lhi * 4 + r];

  i32x4 pf[8];
#pragma unroll
  for (int k2 = 0; k2 < 8; ++k2)
    pf[k2] = *(const i32x4*)&plds[llo * 264 + k2 * 32 + lhi * 8];

#pragma unroll
  for (int hh = 0; hh < 2; ++hh) {
    f32x4 cacc[16];
#pragma unroll
    for (int hn = 0; hn < 16; ++hn) cacc[hn] = (f32x4){0.f, 0.f, 0.f, 0.f};
#pragma unroll
    for (int k2 = 0; k2 < 8; ++k2) {
      const unsigned short* tb = encT_bf + ((size_t)b * HH + hh * 256 + llo) * TE + k2 * 32 + lhi * 8;
#pragma unroll
      for (int hn = 0; hn < 16; ++hn)
        cacc[hn] = mfma_bf16(pf[k2], *(const i32x4*)(tb + (size_t)hn * 16 * TE), cacc[hn]);
    }
#pragma unroll
    for (int hn = 0; hn < 16; ++hn)
#pragma unroll
      for (int r = 0; r < 4; ++r) {
        const float vv = mq[r] ? cacc[hn][r] * rinv[r] : 0.0f;
        out[((size_t)b * TD + q0 + lhi * 4 + r) * HH + hh * 256 + hn * 16 + llo] = vv;
      }
  }
}

extern "C" void kernel_launch(void* const* d_in, const int* in_sizes, int n_in,
                              void* d_out, int out_size, void* d_ws, size_t ws_size,
                              hipStream_t stream) {
  const float* enc  = (const float*)d_in[0];
  const int*   ids  = (const int*)d_in[1];
  const float* h0   = (const float*)d_in[2];
  const float* c0   = (const float*)d_in[3];
  const float* E    = (const float*)d_in[4];
  const float* W    = (const float*)d_in[5];
  const float* U    = (const float*)d_in[6];
  const float* bias = (const float*)d_in[7];
  float* out = (float*)d_out;
  char* ws = (char*)d_ws;

  unsigned short* enc_bf  = (unsigned short*)(ws + WS_ENC);
  unsigned short* encT_bf = (unsigned short*)(ws + WS_ENCT);
  unsigned short* dec_bf  = (unsigned short*)(ws + WS_DEC);
  unsigned short* h_ping  = (unsigned short*)(ws + WS_HPING);
  unsigned*       cnt     = (unsigned*)(ws + WS_CNT);
  unsigned short* wT      = (unsigned short*)(ws + WS_WT);
  unsigned short* xseq    = (unsigned short*)(ws + WS_XSEQ);

  enc_prep<<<2048, 256, 0, stream>>>(enc, enc_bf, encT_bf);
  w_prep<<<384, 256, 0, stream>>>(W, U, wT);
  x_prep<<<16384, 64, 0, stream>>>(E, ids, xseq);
  h0_prep<<<128, 256, 0, stream>>>(h0, h_ping, cnt);
  lstm_kernel<<<32, 64, 0, stream>>>(xseq, ids, h0, c0, wT, bias, h_ping, dec_bf, out, cnt);
  attn_kernel<<<1024, 64, 0, stream>>>(dec_bf, enc_bf, encT_bf, ids, out);
}

// Round 18
// 1889.602 us; speedup vs baseline: 2.1133x; 2.1133x over previous
//
#include <hip/hip_runtime.h>
#include <stdint.h>

typedef __attribute__((ext_vector_type(4))) float f32x4;
typedef __attribute__((ext_vector_type(4))) int i32x4;
typedef __attribute__((ext_vector_type(4))) unsigned short u16x4;
typedef __attribute__((ext_vector_type(8))) __bf16 bf16x8;

#define NB 64
#define TD 256
#define TE 256
#define HH 512
#define DD 256
#define FH 2048
#define KT 768
#define LDK 776  // LDS row stride (bf16)

// workspace layout (bytes)
#define WS_ENC   0u          // ushort [NB][TE][HH]   enc bf16
#define WS_ENCT  16777216u   // ushort [NB][HH][TE]   enc transposed bf16
#define WS_DEC   33554432u   // ushort [NB][TD][HH]   dec_outputs bf16
#define WS_HPING 50331648u   // ushort [2][NB][HH]    h ping-pong bf16
#define WS_CNT   50462720u   // uint   [2][TD]        arrival counters
#define WS_WT    50528256u   // ushort [FH][KT]       W|U transposed bf16 (3MB)
#define WS_XSEQ  53673984u   // ushort [TD][NB][DD]   precomputed x bf16 (8MB)

#define OUT_HT 8388608u      // B*TD*H
#define OUT_CT 8421376u

__device__ inline unsigned short f2b(float f) {
  union { float f; unsigned u; } x; x.f = f;
  unsigned r = x.u + 0x7FFFu + ((x.u >> 16) & 1u);   // RNE
  return (unsigned short)(r >> 16);
}
__device__ inline float sigm(float x)   { return 1.0f / (1.0f + __expf(-x)); }
__device__ inline float tanhf_(float x) { return 1.0f - 2.0f / (__expf(2.0f * x) + 1.0f); }

__device__ inline f32x4 mfma_bf16(i32x4 a, i32x4 b, f32x4 c) {
  return __builtin_amdgcn_mfma_f32_16x16x32_bf16(
      __builtin_bit_cast(bf16x8, a), __builtin_bit_cast(bf16x8, b), c, 0, 0, 0);
}

// ---- L3-coherent primitives (bypass L1/L2: sc0 sc1) ----
__device__ inline unsigned poll_word(const unsigned* p) {
  unsigned v;
  asm volatile("global_load_dword %0, %1, off sc0 sc1\n\ts_waitcnt vmcnt(0)"
               : "=v"(v) : "v"(p) : "memory");
  return v;
}
__device__ inline i32x4 load4_bypass(const void* p) {  // NO waitcnt inside
  i32x4 v;
  asm volatile("global_load_dwordx4 %0, %1, off sc0 sc1" : "=v"(v) : "v"(p) : "memory");
  return v;
}
__device__ inline void store4_wt(void* p, i32x4 v) {  // 16B write-through
  asm volatile("global_store_dwordx4 %0, %1, off sc0 sc1" :: "v"(p), "v"(v) : "memory");
}
__device__ inline void store_u16_wt(unsigned short* p, unsigned v) {  // 2B write-through
  asm volatile("global_store_short %0, %1, off sc0 sc1" :: "v"(p), "v"(v) : "memory");
}
__device__ inline void vm_drain() {
  asm volatile("s_waitcnt vmcnt(0)" ::: "memory");
}
__device__ inline void lds_fence() {
  asm volatile("s_waitcnt lgkmcnt(0)" ::: "memory");
}

// ---------------- prepass: enc -> bf16 + transposed bf16 ----------------
__global__ __launch_bounds__(256) void enc_prep(const float* __restrict__ enc,
                                                unsigned short* __restrict__ enc_bf,
                                                unsigned short* __restrict__ encT_bf) {
  __shared__ float tile[64][65];
  const int bid = blockIdx.x;
  const int b  = bid >> 5;
  const int kt = (bid >> 3) & 3;
  const int ht = bid & 7;
  const int tr = threadIdx.x >> 6;
  const int tc = threadIdx.x & 63;
#pragma unroll
  for (int i = 0; i < 16; ++i) {
    const int ke = i * 4 + tr;
    const float v = enc[((size_t)b * TE + kt * 64 + ke) * HH + ht * 64 + tc];
    enc_bf[((size_t)b * TE + kt * 64 + ke) * HH + ht * 64 + tc] = f2b(v);
    tile[ke][tc] = v;
  }
  __syncthreads();
  const int hr4 = threadIdx.x >> 4;
  const int k4  = (threadIdx.x & 15) * 4;
#pragma unroll
  for (int jr = 0; jr < 4; ++jr) {
    const int hr = jr * 16 + hr4;
    u16x4 p = { f2b(tile[k4 + 0][hr]), f2b(tile[k4 + 1][hr]),
                f2b(tile[k4 + 2][hr]), f2b(tile[k4 + 3][hr]) };
    *(u16x4*)&encT_bf[((size_t)b * HH + ht * 64 + hr) * TE + kt * 64 + k4] = p;
  }
}

// ---------------- prepass: W|U -> bf16 transposed wT[col][k] ----------------
__global__ __launch_bounds__(256) void w_prep(const float* __restrict__ W,
                                              const float* __restrict__ U,
                                              unsigned short* __restrict__ wT) {
  __shared__ float tile[64][65];
  const int kt = blockIdx.x >> 5;
  const int ct = blockIdx.x & 31;
  const int tr = threadIdx.x >> 6;
  const int tc = threadIdx.x & 63;
#pragma unroll
  for (int i = 0; i < 16; ++i) {
    const int kr = i * 4 + tr;
    const int k  = kt * 64 + kr;
    const float v = (k < DD) ? W[(size_t)k * FH + ct * 64 + tc]
                             : U[(size_t)(k - DD) * FH + ct * 64 + tc];
    tile[kr][tc] = v;
  }
  __syncthreads();
  const int cr4 = threadIdx.x >> 4;
  const int k4  = (threadIdx.x & 15) * 4;
#pragma unroll
  for (int jr = 0; jr < 4; ++jr) {
    const int cr = jr * 16 + cr4;
    u16x4 p = { f2b(tile[k4 + 0][cr]), f2b(tile[k4 + 1][cr]),
                f2b(tile[k4 + 2][cr]), f2b(tile[k4 + 3][cr]) };
    *(u16x4*)&wT[((size_t)ct * 64 + cr) * KT + kt * 64 + k4] = p;
  }
}

// ---------------- prepass: gather x = E[ids] for ALL steps -> xseq[t][b][d] bf16 ----
__global__ __launch_bounds__(64) void x_prep(const float* __restrict__ E,
                                             const int* __restrict__ ids,
                                             unsigned short* __restrict__ xseq) {
  const int bid = blockIdx.x;       // 16384 = 64 b * 256 t
  const int b = bid >> 8;
  const int t = bid & 255;
  const int lane = threadIdx.x;
  const int id = ids[b * TD + t];
  f32x4 v = *(const f32x4*)(E + (size_t)id * DD + lane * 4);
  u16x4 p = { f2b(v[0]), f2b(v[1]), f2b(v[2]), f2b(v[3]) };
  *(u16x4*)&xseq[((size_t)t * NB + b) * DD + lane * 4] = p;
}

// ---------------- prepass: h0 -> bf16, zero counters ----------------
__global__ __launch_bounds__(256) void h0_prep(const float* __restrict__ h0,
                                               unsigned short* __restrict__ h_ping,
                                               unsigned* __restrict__ cnt) {
  const int i = blockIdx.x * 256 + threadIdx.x;
  if (i < NB * HH) h_ping[i] = f2b(h0[i]);
  if (i < 2 * TD) cnt[i] = 0u;
}

// ---------------- persistent masked LSTM ----------------
// 64 blocks = 2 groups(32 batches) x 32 unit-slices(16 units = 64 z-cols).
// All per-step global stores are L3 write-through and covered by ONE drain
// before the flag — nothing outstanding when the next poll runs (vmcnt waits
// oldest-first, so HBM-latency stores would poison every later poll).
__global__ __launch_bounds__(64, 1) void lstm_kernel(
    const unsigned short* __restrict__ xseq, const int* __restrict__ ids,
    const float* __restrict__ h0f, const float* __restrict__ c0f,
    const unsigned short* __restrict__ wT, const float* __restrict__ bias,
    unsigned short* __restrict__ h_ping,
    unsigned short* __restrict__ dec_bf,
    float* __restrict__ out,
    unsigned* __restrict__ cnt)
{
  const int lane = threadIdx.x;
  const int g  = blockIdx.x >> 5;   // group 0/1
  const int s  = blockIdx.x & 31;   // unit slice
  const int u0 = s << 4;
  const int lhi = lane >> 4;        // 0..3
  const int llo = lane & 15;

  __shared__ __align__(16) unsigned short wt[64 * LDK];  // 99.3KB
  __shared__ int ids_l[32][260];                         // 33.3KB
  __shared__ __align__(64) unsigned short hT[32][32];    // 2KB publish-transpose

  // stage weight slice
  {
    const int r = lane;
    const int c = (r >> 4) * 512 + u0 + (r & 15);
    const unsigned short* src = wT + (size_t)c * KT;
#pragma unroll 8
    for (int j = 0; j < 96; ++j)
      *(i32x4*)&wt[r * LDK + j * 8] = *(const i32x4*)(src + j * 8);
  }
  // stage ids for this group's 32 batches
  for (int idx = lane; idx < 32 * 256; idx += 64) {
    const int row = idx >> 8, tt = idx & 255;
    ids_l[row][tt] = ids[(g * 32 + row) * TD + tt];
  }
  __syncthreads();

  float bb[4];
#pragma unroll
  for (int gg = 0; gg < 4; ++gg) bb[gg] = bias[gg * 512 + u0 + llo];

  float h_reg[2][4], c_reg[2][4];
#pragma unroll
  for (int mt = 0; mt < 2; ++mt)
#pragma unroll
    for (int r = 0; r < 4; ++r) {
      const int b = g * 32 + mt * 16 + lhi * 4 + r;
      h_reg[mt][r] = h0f[b * HH + u0 + llo];
      c_reg[mt][r] = c0f[b * HH + u0 + llo];
    }

  unsigned short* hp0 = h_ping;
  unsigned short* hp1 = h_ping + NB * HH;

  for (int t = 0; t < TD; ++t) {
    const unsigned short* h_src = (t & 1) ? hp1 : hp0;
    unsigned short*       h_dst = (t & 1) ? hp0 : hp1;

    int mid[2][4];
#pragma unroll
    for (int mt = 0; mt < 2; ++mt)
#pragma unroll
      for (int r = 0; r < 4; ++r) mid[mt][r] = ids_l[mt * 16 + lhi * 4 + r][t];

    // x fragments: sequential bf16 loads from precomputed xseq
    const unsigned short* xp = xseq + ((size_t)t * NB + g * 32) * DD;
    i32x4 xf[2][8];
#pragma unroll
    for (int mt = 0; mt < 2; ++mt) {
      const unsigned short* xr = xp + (mt * 16 + llo) * DD + lhi * 8;
#pragma unroll
      for (int kk = 0; kk < 8; ++kk)
        xf[mt][kk] = *(const i32x4*)(xr + kk * 32);
    }

    // x-part MFMAs (K = 0..255) — before waiting on peers
    f32x4 acc[2][4];
#pragma unroll
    for (int mt = 0; mt < 2; ++mt)
#pragma unroll
      for (int gg = 0; gg < 4; ++gg) acc[mt][gg] = (f32x4){0.f, 0.f, 0.f, 0.f};
#pragma unroll
    for (int kk = 0; kk < 8; ++kk) {
      const int ko = kk * 32 + lhi * 8;
#pragma unroll
      for (int gg = 0; gg < 4; ++gg) {
        i32x4 bfr = *(const i32x4*)&wt[(gg * 16 + llo) * LDK + ko];
        acc[0][gg] = mfma_bf16(xf[0][kk], bfr, acc[0][gg]);
        acc[1][gg] = mfma_bf16(xf[1][kk], bfr, acc[1][gg]);
      }
    }

    // wait for previous step's h: hot-spin on the SINGLE arrival counter
    if (t > 0) {
      const unsigned* c = cnt + (size_t)g * TD + (t - 1);
      while (poll_word(c) < 32u) { /* hot spin: wave-merged single-dword poll */ }
    }

    // h-part MFMAs (K = 256..767): issue all bypass loads, one drain, then MFMA
    {
      const unsigned short* hb0 = h_src + (size_t)(g * 32 + llo) * HH + lhi * 8;
      const unsigned short* hb1 = hb0 + 16 * HH;
      i32x4 ha0[16], ha1[16];
#pragma unroll
      for (int kk = 0; kk < 16; ++kk) {
        ha0[kk] = load4_bypass(hb0 + kk * 32);
        ha1[kk] = load4_bypass(hb1 + kk * 32);
      }
      vm_drain();
      __builtin_amdgcn_sched_barrier(0);  // rule #18: keep MFMAs after the waitcnt
#pragma unroll
      for (int kk = 0; kk < 16; ++kk) {
        const int ko = DD + kk * 32 + lhi * 8;
#pragma unroll
        for (int gg = 0; gg < 4; ++gg) {
          i32x4 bfr = *(const i32x4*)&wt[(gg * 16 + llo) * LDK + ko];
          acc[0][gg] = mfma_bf16(ha0[kk], bfr, acc[0][gg]);
          acc[1][gg] = mfma_bf16(ha1[kk], bfr, acc[1][gg]);
        }
      }
    }

    // epilogue: gates, state update; h -> LDS transpose tile; dec stores NOW
    // (write-through, acks overlap with the h-publish drain below)
    unsigned hb_out[2][4];
#pragma unroll
    for (int mt = 0; mt < 2; ++mt) {
#pragma unroll
      for (int r = 0; r < 4; ++r) {
        const float zi = acc[mt][0][r] + bb[0];
        const float zf = acc[mt][1][r] + bb[1];
        const float zg = acc[mt][2][r] + bb[2];
        const float zo = acc[mt][3][r] + bb[3];
        const float cn = sigm(zf) * c_reg[mt][r] + sigm(zi) * tanhf_(zg);
        const float hn = sigm(zo) * tanhf_(cn);
        if (mid[mt][r] != 0) { c_reg[mt][r] = cn; h_reg[mt][r] = hn; }
        const unsigned hb = f2b(h_reg[mt][r]);
        hb_out[mt][r] = hb;
        hT[mt * 16 + lhi * 4 + r][llo] = (unsigned short)hb;
        const int b = g * 32 + mt * 16 + lhi * 4 + r;
        store_u16_wt(&dec_bf[((size_t)b * TD + t) * HH + u0 + llo], hb);
      }
    }

    if (t < TD - 1) {
      lds_fence();
      __builtin_amdgcn_sched_barrier(0);
      // coalesced publish: one 16B sector-aligned store per lane
      const int br = lane >> 1;
      const int half = lane & 1;
      i32x4 hv = *(const i32x4*)&hT[br][half * 8];
      store4_wt(h_dst + (size_t)(g * 32 + br) * HH + u0 + half * 8, hv);
      vm_drain();  // covers h publish AND dec stores -> nothing outstanding at next poll
      if (lane == 0)
        __hip_atomic_fetch_add(cnt + (size_t)g * TD + t, 1u,
                               __ATOMIC_RELEASE, __HIP_MEMORY_SCOPE_AGENT);
    }
  }

#pragma unroll
  for (int mt = 0; mt < 2; ++mt)
#pragma unroll
    for (int r = 0; r < 4; ++r) {
      const int b = g * 32 + mt * 16 + lhi * 4 + r;
      out[OUT_HT + (size_t)b * HH + u0 + llo] = h_reg[mt][r];
      out[OUT_CT + (size_t)b * HH + u0 + llo] = c_reg[mt][r];
    }
}

// ---------------- fused attention: scores -> softmax -> ctx ----------------
__global__ __launch_bounds__(64, 1) void attn_kernel(
    const unsigned short* __restrict__ dec_bf,
    const unsigned short* __restrict__ enc_bf,
    const unsigned short* __restrict__ encT_bf,
    const int* __restrict__ ids,
    float* __restrict__ out)
{
  const int lane = threadIdx.x;
  const int b  = blockIdx.x >> 4;
  const int q0 = (blockIdx.x & 15) << 4;
  const int lhi = lane >> 4, llo = lane & 15;

  __shared__ __align__(16) unsigned short plds[16 * 264];

  i32x4 qf[16];
  const unsigned short* qb = dec_bf + ((size_t)b * TD + q0 + llo) * HH + lhi * 8;
#pragma unroll
  for (int kk = 0; kk < 16; ++kk) qf[kk] = *(const i32x4*)(qb + kk * 32);

  f32x4 sc[16];
#pragma unroll
  for (int ke = 0; ke < 16; ++ke) sc[ke] = (f32x4){0.f, 0.f, 0.f, 0.f};
#pragma unroll
  for (int kk = 0; kk < 16; ++kk) {
    const unsigned short* eb = enc_bf + ((size_t)b * TE + llo) * HH + kk * 32 + lhi * 8;
#pragma unroll
    for (int ke = 0; ke < 16; ++ke)
      sc[ke] = mfma_bf16(qf[kk], *(const i32x4*)(eb + (size_t)ke * 16 * HH), sc[ke]);
  }

  float mx[4], rinv[4];
#pragma unroll
  for (int r = 0; r < 4; ++r) {
    float m = sc[0][r];
#pragma unroll
    for (int ke = 1; ke < 16; ++ke) m = fmaxf(m, sc[ke][r]);
#pragma unroll
    for (int off = 1; off <= 8; off <<= 1) m = fmaxf(m, __shfl_xor(m, off));
    mx[r] = m;
  }
  float sm[4] = {0.f, 0.f, 0.f, 0.f};
#pragma unroll
  for (int ke = 0; ke < 16; ++ke)
#pragma unroll
    for (int r = 0; r < 4; ++r) {
      const float p = __expf(sc[ke][r] - mx[r]);
      sc[ke][r] = p;
      sm[r] += p;
    }
#pragma unroll
  for (int r = 0; r < 4; ++r) {
    float ss = sm[r];
#pragma unroll
    for (int off = 1; off <= 8; off <<= 1) ss += __shfl_xor(ss, off);
    rinv[r] = 1.0f / ss;
  }

#pragma unroll
  for (int ke = 0; ke < 16; ++ke)
#pragma unroll
    for (int r = 0; r < 4; ++r)
      plds[(lhi * 4 + r) * 264 + ke * 16 + llo] = f2b(sc[ke][r]);
  __syncthreads();

  int mq[4];
#pragma unroll
  for (int r = 0; r < 4; ++r) mq[r] = ids[b * TD + q0 + lhi * 4 + r];

  i32x4 pf[8];
#pragma unroll
  for (int k2 = 0; k2 < 8; ++k2)
    pf[k2] = *(const i32x4*)&plds[llo * 264 + k2 * 32 + lhi * 8];

#pragma unroll
  for (int hh = 0; hh < 2; ++hh) {
    f32x4 cacc[16];
#pragma unroll
    for (int hn = 0; hn < 16; ++hn) cacc[hn] = (f32x4){0.f, 0.f, 0.f, 0.f};
#pragma unroll
    for (int k2 = 0; k2 < 8; ++k2) {
      const unsigned short* tb = encT_bf + ((size_t)b * HH + hh * 256 + llo) * TE + k2 * 32 + lhi * 8;
#pragma unroll
      for (int hn = 0; hn < 16; ++hn)
        cacc[hn] = mfma_bf16(pf[k2], *(const i32x4*)(tb + (size_t)hn * 16 * TE), cacc[hn]);
    }
#pragma unroll
    for (int hn = 0; hn < 16; ++hn)
#pragma unroll
      for (int r = 0; r < 4; ++r) {
        const float vv = mq[r] ? cacc[hn][r] * rinv[r] : 0.0f;
        out[((size_t)b * TD + q0 + lhi * 4 + r) * HH + hh * 256 + hn * 16 + llo] = vv;
      }
  }
}

extern "C" void kernel_launch(void* const* d_in, const int* in_sizes, int n_in,
                              void* d_out, int out_size, void* d_ws, size_t ws_size,
                              hipStream_t stream) {
  const float* enc  = (const float*)d_in[0];
  const int*   ids  = (const int*)d_in[1];
  const float* h0   = (const float*)d_in[2];
  const float* c0   = (const float*)d_in[3];
  const float* E    = (const float*)d_in[4];
  const float* W    = (const float*)d_in[5];
  const float* U    = (const float*)d_in[6];
  const float* bias = (const float*)d_in[7];
  float* out = (float*)d_out;
  char* ws = (char*)d_ws;

  unsigned short* enc_bf  = (unsigned short*)(ws + WS_ENC);
  unsigned short* encT_bf = (unsigned short*)(ws + WS_ENCT);
  unsigned short* dec_bf  = (unsigned short*)(ws + WS_DEC);
  unsigned short* h_ping  = (unsigned short*)(ws + WS_HPING);
  unsigned*       cnt     = (unsigned*)(ws + WS_CNT);
  unsigned short* wT      = (unsigned short*)(ws + WS_WT);
  unsigned short* xseq    = (unsigned short*)(ws + WS_XSEQ);

  enc_prep<<<2048, 256, 0, stream>>>(enc, enc_bf, encT_bf);
  w_prep<<<384, 256, 0, stream>>>(W, U, wT);
  x_prep<<<16384, 64, 0, stream>>>(E, ids, xseq);
  h0_prep<<<128, 256, 0, stream>>>(h0, h_ping, cnt);
  lstm_kernel<<<64, 64, 0, stream>>>(xseq, ids, h0, c0, wT, bias, h_ping, dec_bf, out, cnt);
  attn_kernel<<<1024, 64, 0, stream>>>(dec_bf, enc_bf, encT_bf, ids, out);
}